// Round 9
// baseline (665.197 us; speedup 1.0000x reference)
//
#include <hip/hip_runtime.h>
#include <hip/hip_cooperative_groups.h>
#include <math.h>

namespace cg = cooperative_groups;

typedef unsigned short ushort_t;
typedef short bf8_t __attribute__((ext_vector_type(8)));   // 8 bf16 in 4 VGPRs
typedef float f4_t  __attribute__((ext_vector_type(4)));

// Problem dims
constexpr int B_   = 4;
constexpr int L_   = 1024;
constexpr int DIN_ = 64;
constexpr int DOUT_= 10;
constexpr int D_   = 512;
constexpr int N_   = 16;
constexpr int R_   = 32;
constexpr int RN_  = 64;          // R + 2N
constexpr int M_   = B_ * L_;     // 4096 rows (b,l) flattened

// Chunked scan config
constexpr int CN_ = 64;           // chunks over L
constexpr int CL_ = L_ / CN_;     // 16 steps per chunk

// Intermediates (device globals; referenced ONLY inside device code).
__device__ float    g_h   [M_ * D_];    // hidden fp32 (layer-1 input / residual)
__device__ float    g_h2  [M_ * D_];    // hidden fp32 (layer-2 input / residual)
__device__ ushort_t g_hbf [M_ * D_];    // bf16 copy of current hidden
__device__ ushort_t g_gelubf[M_ * D_];  // bf16(gelu(mamba_y)) (mix A-operand)
__device__ float    g_stL  [B_ * CN_ * D_ * N_];
__device__ float    g_sumd [B_ * CN_ * D_];
__device__ float    g_carry[B_ * CN_ * D_ * N_];
__device__ float    g_mean [B_ * D_];   // column sums of final hidden (atomics)
__device__ int      g_cntm;             // mix2 tail counter
// bf16 weights (re-converted each call)
__device__ ushort_t g_w1bf [D_ * D_];
__device__ ushort_t g_w2bf [D_ * D_];
__device__ ushort_t g_xp1bf[RN_ * D_];
__device__ ushort_t g_xp2bf[RN_ * D_];

__device__ __forceinline__ float gelu_f(float x) {
  return 0.5f * x * (1.0f + erff(x * 0.7071067811865475f));
}
__device__ __forceinline__ float softplus_f(float x) {
  return fmaxf(x, 0.0f) + log1pf(__expf(-fabsf(x)));
}
__device__ __forceinline__ ushort_t f2bf(float x) {  // RNE fp32->bf16
  union { float f; unsigned u; } v; v.f = x;
  unsigned r = v.u + 0x7fffu + ((v.u >> 16) & 1u);
  return (ushort_t)(r >> 16);
}

// ---------------------------------------------------------------------------
// k_pre: blocks [0,512)   = in-projection bf16 MFMA (x @ W_in^T + b)
//        blocks [512,1088)= weight fp32->bf16 conversion
//        block  1088      = zero g_mean + tail counter
// ---------------------------------------------------------------------------
__device__ __forceinline__ void in_mfma_part(int bx,
                                             const float* __restrict__ x,
                                             const float* __restrict__ w,
                                             const float* __restrict__ bias) {
  __shared__ ushort_t As[64][72];
  __shared__ ushort_t Bs[64][72];
  const int tid  = threadIdx.x;
  const int m0   = (bx >> 3) * 64;
  const int n0   = (bx & 7) * 64;
  const int lane = tid & 63;
  const int wv   = tid >> 6;
  const int quad = lane >> 4;
  const int ln   = lane & 15;
  const int mw   = (wv & 1) * 32;
  const int nw   = (wv >> 1) * 32;

  {
    const int m = tid >> 2, q = (tid & 3) << 4;
#pragma unroll
    for (int i = 0; i < 4; ++i) {
      float4 va = *(const float4*)&x[(size_t)(m0 + m) * 64 + q + i * 4];
      float4 vb = *(const float4*)&w[(size_t)(n0 + m) * 64 + q + i * 4];
      ushort4 oa, ob;
      oa.x = f2bf(va.x); oa.y = f2bf(va.y); oa.z = f2bf(va.z); oa.w = f2bf(va.w);
      ob.x = f2bf(vb.x); ob.y = f2bf(vb.y); ob.z = f2bf(vb.z); ob.w = f2bf(vb.w);
      *(ushort4*)&As[m][q + i * 4] = oa;
      *(ushort4*)&Bs[m][q + i * 4] = ob;
    }
  }
  __syncthreads();

  f4_t acc[2][2] = {};
#pragma unroll
  for (int k1 = 0; k1 < 64; k1 += 32) {
    bf8_t a0 = *(const bf8_t*)&As[mw +      ln][k1 + quad * 8];
    bf8_t a1 = *(const bf8_t*)&As[mw + 16 + ln][k1 + quad * 8];
    bf8_t b0 = *(const bf8_t*)&Bs[nw +      ln][k1 + quad * 8];
    bf8_t b1 = *(const bf8_t*)&Bs[nw + 16 + ln][k1 + quad * 8];
    acc[0][0] = __builtin_amdgcn_mfma_f32_16x16x32_bf16(a0, b0, acc[0][0], 0, 0, 0);
    acc[0][1] = __builtin_amdgcn_mfma_f32_16x16x32_bf16(a0, b1, acc[0][1], 0, 0, 0);
    acc[1][0] = __builtin_amdgcn_mfma_f32_16x16x32_bf16(a1, b0, acc[1][0], 0, 0, 0);
    acc[1][1] = __builtin_amdgcn_mfma_f32_16x16x32_bf16(a1, b1, acc[1][1], 0, 0, 0);
  }

  float bj[2] = { bias[n0 + nw + ln], bias[n0 + nw + 16 + ln] };
#pragma unroll
  for (int i = 0; i < 2; ++i)
#pragma unroll
    for (int j = 0; j < 2; ++j) {
      const int nc = n0 + nw + 16 * j + ln;
#pragma unroll
      for (int r = 0; r < 4; ++r) {
        const int row = m0 + mw + 16 * i + quad * 4 + r;
        const size_t idx = (size_t)row * D_ + nc;
        float v = acc[i][j][r] + bj[j];
        g_h[idx] = v;
        g_hbf[idx] = f2bf(v);
      }
    }
}

__global__ __launch_bounds__(256) void k_pre(const float* __restrict__ x,
                                             const float* __restrict__ w_in,
                                             const float* __restrict__ b_in,
                                             const float* __restrict__ w1,
                                             const float* __restrict__ w2,
                                             const float* __restrict__ xp1,
                                             const float* __restrict__ xp2) {
  const int bx = blockIdx.x;
  if (bx < 512) { in_mfma_part(bx, x, w_in, b_in); return; }
  if (bx == 1088) {                 // zero mean accumulator + counter
#pragma unroll
    for (int j = 0; j < 8; ++j) g_mean[threadIdx.x * 8 + j] = 0.0f;
    if (threadIdx.x == 0) g_cntm = 0;
    return;
  }
  int i = ((bx - 512) * 256 + threadIdx.x) * 4;
  const float* src; ushort_t* dst; int off;
  if (i < 262144)      { src = w1;  dst = g_w1bf;  off = i; }
  else if (i < 524288) { src = w2;  dst = g_w2bf;  off = i - 262144; }
  else if (i < 557056) { src = xp1; dst = g_xp1bf; off = i - 524288; }
  else                 { src = xp2; dst = g_xp2bf; off = i - 557056; }
  float4 v = *(const float4*)&src[off];
  ushort4 o; o.x = f2bf(v.x); o.y = f2bf(v.y); o.z = f2bf(v.z); o.w = f2bf(v.w);
  *(ushort4*)&dst[off] = o;
}

// ---------------------------------------------------------------------------
// bf16 MFMA GEMM (K=512), 64x64 tile, 4 waves, 2x2 16x16x32 MFMA per wave.
// EPIM: 1 = +bias +res. DUAL: also store bf16. MEAN: col sums into g_mean.
// ---------------------------------------------------------------------------
template<int EPIM, bool DUAL, bool MEAN>
__device__ __forceinline__ void gemm_bf16_dev(
    const ushort_t* __restrict__ Abf, const ushort_t* __restrict__ Wbf,
    const float* __restrict__ bias, const float* __restrict__ res,
    float* __restrict__ out, ushort_t* __restrict__ obf) {
  __shared__ ushort_t As[64][72];
  __shared__ ushort_t Bs[64][72];
  const int tid  = threadIdx.x;
  const int m0   = (blockIdx.x >> 3) * 64;
  const int n0   = (blockIdx.x & 7) * 64;
  const int lane = tid & 63;
  const int wv   = tid >> 6;
  const int quad = lane >> 4;
  const int ln   = lane & 15;
  const int mw   = (wv & 1) * 32;
  const int nw   = (wv >> 1) * 32;

  f4_t acc[2][2] = {};

  for (int k0 = 0; k0 < 512; k0 += 64) {
#pragma unroll
    for (int c = 0; c < 2; ++c) {
      int idx = tid + c * 256;                 // 512 chunks of 8 bf16
      int m = idx >> 3, kq = (idx & 7) << 3;
      *(float4*)&As[m][kq] = *(const float4*)&Abf[(size_t)(m0 + m) * 512 + k0 + kq];
      *(float4*)&Bs[m][kq] = *(const float4*)&Wbf[(size_t)(n0 + m) * 512 + k0 + kq];
    }
    __syncthreads();
#pragma unroll
    for (int k1 = 0; k1 < 64; k1 += 32) {
      bf8_t a0 = *(const bf8_t*)&As[mw +      ln][k1 + quad * 8];
      bf8_t a1 = *(const bf8_t*)&As[mw + 16 + ln][k1 + quad * 8];
      bf8_t b0 = *(const bf8_t*)&Bs[nw +      ln][k1 + quad * 8];
      bf8_t b1 = *(const bf8_t*)&Bs[nw + 16 + ln][k1 + quad * 8];
      acc[0][0] = __builtin_amdgcn_mfma_f32_16x16x32_bf16(a0, b0, acc[0][0], 0, 0, 0);
      acc[0][1] = __builtin_amdgcn_mfma_f32_16x16x32_bf16(a0, b1, acc[0][1], 0, 0, 0);
      acc[1][0] = __builtin_amdgcn_mfma_f32_16x16x32_bf16(a1, b0, acc[1][0], 0, 0, 0);
      acc[1][1] = __builtin_amdgcn_mfma_f32_16x16x32_bf16(a1, b1, acc[1][1], 0, 0, 0);
    }
    __syncthreads();
  }

  float bj[2] = { bias[n0 + nw + ln], bias[n0 + nw + 16 + ln] };
  float psum[2][2] = {{0.f, 0.f}, {0.f, 0.f}};
#pragma unroll
  for (int i = 0; i < 2; ++i)
#pragma unroll
    for (int j = 0; j < 2; ++j) {
      const int nc = n0 + nw + 16 * j + ln;
#pragma unroll
      for (int r = 0; r < 4; ++r) {
        const int row = m0 + mw + 16 * i + quad * 4 + r;
        const size_t idx = (size_t)row * D_ + nc;
        float v = acc[i][j][r] + bj[j] + res[idx];
        out[idx] = v;
        if constexpr (DUAL) obf[idx] = f2bf(v);
        if constexpr (MEAN) psum[i][j] += v;
      }
    }
  if constexpr (MEAN) {
    __shared__ float ssum[16][64];
#pragma unroll
    for (int i = 0; i < 2; ++i)
#pragma unroll
      for (int j = 0; j < 2; ++j) {
        const int rg = (wv & 1) * 8 + i * 4 + quad;
        const int cl = (wv >> 1) * 32 + j * 16 + ln;
        ssum[rg][cl] = psum[i][j];
      }
    __syncthreads();
    if (tid < 64) {
      float s = 0.f;
#pragma unroll
      for (int rg = 0; rg < 16; ++rg) s += ssum[rg][tid];
      const int b = m0 >> 10;
      atomicAdd(&g_mean[b * D_ + n0 + tid], s);
    }
  }
}

__global__ __launch_bounds__(256) void k_mix1g(const float* __restrict__ bias) {
  gemm_bf16_dev<1, true, false>(g_gelubf, g_w1bf, bias, g_h, g_h2, g_hbf);
}

// mix2 + fused head (tail-block: mean-normalize + out-proj; small work, OK)
__global__ __launch_bounds__(256) void k_mix2g(const float* __restrict__ bias,
                                               const float* __restrict__ out_w,
                                               const float* __restrict__ out_b,
                                               float* __restrict__ outp) {
  gemm_bf16_dev<1, false, true>(g_gelubf, g_w2bf, bias, g_h2, g_h, nullptr);

  __threadfence();                       // release: g_mean atomics done
  __shared__ int lastm;
  if (threadIdx.x == 0) lastm = (atomicAdd(&g_cntm, 1) == 511) ? 1 : 0;
  __syncthreads();
  if (!lastm) return;
  __threadfence();                       // acquire

  const int tid = threadIdx.x;
  __shared__ float smean[4][D_];
  __shared__ float sp[4][DOUT_][16];
  for (int i = tid; i < B_ * D_; i += 256)
    smean[i >> 9][i & 511] = g_mean[i] * (1.0f / L_);
  __syncthreads();
#pragma unroll
  for (int b = 0; b < B_; ++b)
    if (tid < DOUT_ * 16) {
      int o = tid >> 4, seg = tid & 15;
      float p = 0.0f;
#pragma unroll
      for (int i = 0; i < 32; ++i)
        p += smean[b][seg * 32 + i] * out_w[o * D_ + seg * 32 + i];
      sp[b][o][seg] = p;
    }
  __syncthreads();
  if (tid < B_ * DOUT_) {
    int b = tid / DOUT_, o = tid % DOUT_;
    float v = out_b[o];
#pragma unroll
    for (int j = 0; j < 16; ++j) v += sp[b][o][j];
    outp[b * DOUT_ + o] = v;
  }
}

// ---------------------------------------------------------------------------
// Cooperative per-layer kernel. 256 blocks x 512 thr (1 block/CU, LDS 87KB).
//   ph0: stage hbf-tile + xproj to LDS; fused xdbl MFMA -> sx (persists in LDS)
//   ph1: delta-proj + local scan -> stL/sumd
//   grid.sync
//   ph2: carry, ALL blocks: 1 thread per (b,d,n) chain (tid<128), prefetch x16
//   grid.sync
//   ph3: recompute delta from sx, seeded re-scan, emit bf16(gelu(y))
// No arrays live across the syncs (R6 spill lesson); sx survives in LDS.
// ---------------------------------------------------------------------------
__device__ __forceinline__ void load_A(const float* __restrict__ Alog, int d,
                                       float* A) {
#pragma unroll
  for (int n = 0; n < 16; n += 4) {
    float4 t = *(const float4*)&Alog[d * N_ + n];
    A[n + 0] = -__expf(t.x); A[n + 1] = -__expf(t.y);
    A[n + 2] = -__expf(t.z); A[n + 3] = -__expf(t.w);
  }
}

__device__ __forceinline__ void layer_coop_dev(const float* __restrict__ h,
                                               const ushort_t* __restrict__ xpbf,
                                               const float* __restrict__ dtw,
                                               const float* __restrict__ dtb,
                                               const float* __restrict__ Alog,
                                               const float* __restrict__ Dp,
                                               ushort_t* __restrict__ ybf) {
  cg::grid_group grid = cg::this_grid();
  __shared__ ushort_t As[16][520];   // hbf tile (16 x 512, +8 pad)
  __shared__ ushort_t Bs[64][520];   // xproj (64 x 512, +8 pad)
  __shared__ float    sx[16][65];    // xdbl tile fp32 (dt|B|C) — persists
  const int tid  = threadIdx.x;      // 0..511
  const int c    = blockIdx.x & (CN_ - 1);
  const int b    = blockIdx.x >> 6;
  const int row0 = b * L_ + c * CL_;
  const int lane = tid & 63;
  const int wv   = tid >> 6;
  const int quad = lane >> 4;
  const int ln   = lane & 15;
  const int d    = tid;

  // ---- phase 0: staging + fused xdbl MFMA (proven in R8) ----
#pragma unroll
  for (int i = 0; i < 2; ++i) {
    int idx = tid + i * 512;
    int m = idx >> 6, kq = (idx & 63) << 3;
    *(float4*)&As[m][kq] = *(const float4*)&g_hbf[(size_t)(row0 + m) * 512 + kq];
  }
#pragma unroll
  for (int i = 0; i < 8; ++i) {
    int idx = tid + i * 512;
    int m = idx >> 6, kq = (idx & 63) << 3;
    *(float4*)&Bs[m][kq] = *(const float4*)&xpbf[(size_t)m * 512 + kq];
  }
  __syncthreads();

  if (wv < 4) {
    f4_t acc = {};
#pragma unroll
    for (int k0 = 0; k0 < 512; k0 += 32) {
      bf8_t a  = *(const bf8_t*)&As[ln][k0 + quad * 8];
      bf8_t bb = *(const bf8_t*)&Bs[wv * 16 + ln][k0 + quad * 8];
      acc = __builtin_amdgcn_mfma_f32_16x16x32_bf16(a, bb, acc, 0, 0, 0);
    }
#pragma unroll
    for (int r = 0; r < 4; ++r)
      sx[quad * 4 + r][wv * 16 + ln] = acc[r];
  }
  __syncthreads();

  // ---- phase 1: delta-proj + local scan from 0 ----
  {
    float w[32];
#pragma unroll
    for (int r = 0; r < 32; r += 4) {
      float4 t = *(const float4*)&dtw[d * R_ + r];
      w[r] = t.x; w[r + 1] = t.y; w[r + 2] = t.z; w[r + 3] = t.w;
    }
    const float bias = dtb[d];
    float A[16];
    load_A(Alog, d, A);

    float st[16] = {};
    float sumd = 0.0f;
#pragma unroll
    for (int l = 0; l < CL_; ++l) {
      float acc2 = bias;
#pragma unroll
      for (int k = 0; k < 32; ++k) acc2 = fmaf(sx[l][k], w[k], acc2);
      const float delta = softplus_f(acc2);
      const float dh = delta * h[(size_t)(row0 + l) * D_ + d];
      sumd += delta;
#pragma unroll
      for (int n = 0; n < 16; ++n) {
        float dA = __expf(delta * A[n]);
        st[n] = fmaf(dA, st[n], dh * sx[l][32 + n]);
      }
    }
    const size_t o = ((size_t)(b * CN_ + c) * D_ + d) * N_;
#pragma unroll
    for (int n = 0; n < 16; n += 4)
      *(float4*)&g_stL[o + n] = make_float4(st[n], st[n+1], st[n+2], st[n+3]);
    g_sumd[(b * CN_ + c) * D_ + d] = sumd;
  }
  __threadfence();
  grid.sync();

  // ---- phase 2: carry over chunks, full-grid parallelism ----
  if (tid < 128) {
    const int gid = blockIdx.x * 128 + tid;      // 32768 chains
    const int n  = gid & 15;
    const int dd = (gid >> 4) & (D_ - 1);
    const int bb = gid >> 13;
    const float Ac = -__expf(Alog[dd * N_ + n]);
    float carry = 0.0f;
#pragma unroll
    for (int c0 = 0; c0 < CN_; c0 += 16) {
      float s[16], p[16];
#pragma unroll
      for (int j = 0; j < 16; ++j) {
        s[j] = g_stL[((size_t)(bb * CN_ + c0 + j) * D_ + dd) * N_ + n];
        p[j] = g_sumd[(bb * CN_ + c0 + j) * D_ + dd];
      }
#pragma unroll
      for (int j = 0; j < 16; ++j) {
        g_carry[((size_t)(bb * CN_ + c0 + j) * D_ + dd) * N_ + n] = carry;
        carry = fmaf(__expf(Ac * p[j]), carry, s[j]);
      }
    }
  }
  __threadfence();
  grid.sync();

  // ---- phase 3: recompute delta from sx, seeded re-scan, emit ----
  {
    float w[32];
#pragma unroll
    for (int r = 0; r < 32; r += 4) {
      float4 t = *(const float4*)&dtw[d * R_ + r];
      w[r] = t.x; w[r + 1] = t.y; w[r + 2] = t.z; w[r + 3] = t.w;
    }
    const float bias = dtb[d];
    float A[16];
    load_A(Alog, d, A);
    const float Dpv = Dp[d];

    float st[16];
    const size_t o = ((size_t)(b * CN_ + c) * D_ + d) * N_;
#pragma unroll
    for (int n = 0; n < 16; n += 4) {
      float4 t = *(const float4*)&g_carry[o + n];
      st[n] = t.x; st[n+1] = t.y; st[n+2] = t.z; st[n+3] = t.w;
    }
#pragma unroll
    for (int l = 0; l < CL_; ++l) {
      float acc2 = bias;
#pragma unroll
      for (int k = 0; k < 32; ++k) acc2 = fmaf(sx[l][k], w[k], acc2);
      const float delta = softplus_f(acc2);    // bit-identical to phase 1
      const float hv = h[(size_t)(row0 + l) * D_ + d];
      const float dh = delta * hv;
      float y = 0.0f;
#pragma unroll
      for (int n = 0; n < 16; ++n) {
        float dA = __expf(delta * A[n]);
        st[n] = fmaf(dA, st[n], dh * sx[l][32 + n]);
        y = fmaf(st[n], sx[l][48 + n], y);
      }
      ybf[(size_t)(row0 + l) * D_ + d] = f2bf(gelu_f(y + hv * Dpv));
    }
  }
}

__global__ __launch_bounds__(512, 1) void k_layer1(const float* dtw, const float* dtb,
                                                   const float* Alog, const float* Dp) {
  layer_coop_dev(g_h, g_xp1bf, dtw, dtb, Alog, Dp, g_gelubf);
}
__global__ __launch_bounds__(512, 1) void k_layer2(const float* dtw, const float* dtb,
                                                   const float* Alog, const float* Dp) {
  layer_coop_dev(g_h2, g_xp2bf, dtw, dtb, Alog, Dp, g_gelubf);
}

extern "C" void kernel_launch(void* const* d_in, const int* in_sizes, int n_in,
                              void* d_out, int out_size, void* d_ws, size_t ws_size,
                              hipStream_t stream) {
  const float* x        = (const float*)d_in[0];
  const float* W_in     = (const float*)d_in[1];
  const float* b_in     = (const float*)d_in[2];
  const float* mix1_w   = (const float*)d_in[3];
  const float* mix1_b   = (const float*)d_in[4];
  const float* mix2_w   = (const float*)d_in[5];
  const float* mix2_b   = (const float*)d_in[6];
  const float* out_w    = (const float*)d_in[7];
  const float* out_b    = (const float*)d_in[8];
  const float* m1_xproj = (const float*)d_in[9];
  const float* m1_dtw   = (const float*)d_in[10];
  const float* m1_dtb   = (const float*)d_in[11];
  const float* m1_Alog  = (const float*)d_in[12];
  const float* m1_D     = (const float*)d_in[13];
  const float* m2_xproj = (const float*)d_in[14];
  const float* m2_dtw   = (const float*)d_in[15];
  const float* m2_dtb   = (const float*)d_in[16];
  const float* m2_Alog  = (const float*)d_in[17];
  const float* m2_D     = (const float*)d_in[18];
  float* out = (float*)d_out;

  const int gScan = B_ * CN_;                // 256 blocks (coop, 1/CU)
  const int gMix  = (M_ / 64) * (D_ / 64);   // 512

  k_pre<<<1089, 256, 0, stream>>>(x, W_in, b_in, mix1_w, mix2_w, m1_xproj, m2_xproj);

  // ---- layer 1 ----
  {
    void* args[] = { (void*)&m1_dtw, (void*)&m1_dtb, (void*)&m1_Alog, (void*)&m1_D };
    hipLaunchCooperativeKernel((void*)k_layer1, dim3(gScan), dim3(512), args, 0, stream);
  }
  k_mix1g<<<gMix, 256, 0, stream>>>(mix1_b);
  // ---- layer 2 ----
  {
    void* args[] = { (void*)&m2_dtw, (void*)&m2_dtb, (void*)&m2_Alog, (void*)&m2_D };
    hipLaunchCooperativeKernel((void*)k_layer2, dim3(gScan), dim3(512), args, 0, stream);
  }
  k_mix2g<<<gMix, 256, 0, stream>>>(mix2_b, out_w, out_b, out);
}

// Round 10
// 546.150 us; speedup vs baseline: 1.2180x; 1.2180x over previous
//
#include <hip/hip_runtime.h>
#include <math.h>

typedef unsigned short ushort_t;
typedef short bf8_t __attribute__((ext_vector_type(8)));   // 8 bf16 in 4 VGPRs
typedef float f4_t  __attribute__((ext_vector_type(4)));

// Problem dims
constexpr int B_   = 4;
constexpr int L_   = 1024;
constexpr int DIN_ = 64;
constexpr int DOUT_= 10;
constexpr int D_   = 512;
constexpr int N_   = 16;
constexpr int R_   = 32;
constexpr int RN_  = 64;          // R + 2N
constexpr int M_   = B_ * L_;     // 4096 rows (b,l) flattened

// Chunked scan config
constexpr int CN_ = 64;           // chunks over L
constexpr int CL_ = L_ / CN_;     // 16 steps per chunk

// Intermediates (device globals; referenced ONLY inside device code).
__device__ float    g_h   [M_ * D_];    // hidden fp32 (layer-1 input / residual)
__device__ float    g_h2  [M_ * D_];    // hidden fp32 (layer-2 input / residual)
__device__ ushort_t g_hbf [M_ * D_];    // bf16 copy of current hidden
__device__ ushort_t g_gelubf[M_ * D_];  // bf16(gelu(mamba_y)) (mix A-operand)
__device__ float    g_stL  [B_ * CN_ * D_ * N_];
__device__ float    g_sumd [B_ * CN_ * D_];
__device__ float    g_mean [B_ * D_];   // column sums of final hidden (atomics)
__device__ int      g_cntA [8];         // phase-A counters [layer*4 + b]
__device__ int      g_cntm;             // mix2 tail counter
// bf16 weights (re-converted each call)
__device__ ushort_t g_w1bf [D_ * D_];
__device__ ushort_t g_w2bf [D_ * D_];
__device__ ushort_t g_xp1bf[RN_ * D_];
__device__ ushort_t g_xp2bf[RN_ * D_];

__device__ __forceinline__ float gelu_f(float x) {
  return 0.5f * x * (1.0f + erff(x * 0.7071067811865475f));
}
__device__ __forceinline__ float softplus_f(float x) {
  return fmaxf(x, 0.0f) + log1pf(__expf(-fabsf(x)));
}
__device__ __forceinline__ ushort_t f2bf(float x) {  // RNE fp32->bf16
  union { float f; unsigned u; } v; v.f = x;
  unsigned r = v.u + 0x7fffu + ((v.u >> 16) & 1u);
  return (ushort_t)(r >> 16);
}

// ---------------------------------------------------------------------------
// k_pre: blocks [0,512)   = in-projection bf16 MFMA (x @ W_in^T + b)
//        blocks [512,1088)= weight fp32->bf16 conversion
//        block  1088      = zero g_mean + all counters
// ---------------------------------------------------------------------------
__device__ __forceinline__ void in_mfma_part(int bx,
                                             const float* __restrict__ x,
                                             const float* __restrict__ w,
                                             const float* __restrict__ bias) {
  __shared__ ushort_t As[64][72];
  __shared__ ushort_t Bs[64][72];
  const int tid  = threadIdx.x;
  const int m0   = (bx >> 3) * 64;
  const int n0   = (bx & 7) * 64;
  const int lane = tid & 63;
  const int wv   = tid >> 6;
  const int quad = lane >> 4;
  const int ln   = lane & 15;
  const int mw   = (wv & 1) * 32;
  const int nw   = (wv >> 1) * 32;

  {
    const int m = tid >> 2, q = (tid & 3) << 4;
#pragma unroll
    for (int i = 0; i < 4; ++i) {
      float4 va = *(const float4*)&x[(size_t)(m0 + m) * 64 + q + i * 4];
      float4 vb = *(const float4*)&w[(size_t)(n0 + m) * 64 + q + i * 4];
      ushort4 oa, ob;
      oa.x = f2bf(va.x); oa.y = f2bf(va.y); oa.z = f2bf(va.z); oa.w = f2bf(va.w);
      ob.x = f2bf(vb.x); ob.y = f2bf(vb.y); ob.z = f2bf(vb.z); ob.w = f2bf(vb.w);
      *(ushort4*)&As[m][q + i * 4] = oa;
      *(ushort4*)&Bs[m][q + i * 4] = ob;
    }
  }
  __syncthreads();

  f4_t acc[2][2] = {};
#pragma unroll
  for (int k1 = 0; k1 < 64; k1 += 32) {
    bf8_t a0 = *(const bf8_t*)&As[mw +      ln][k1 + quad * 8];
    bf8_t a1 = *(const bf8_t*)&As[mw + 16 + ln][k1 + quad * 8];
    bf8_t b0 = *(const bf8_t*)&Bs[nw +      ln][k1 + quad * 8];
    bf8_t b1 = *(const bf8_t*)&Bs[nw + 16 + ln][k1 + quad * 8];
    acc[0][0] = __builtin_amdgcn_mfma_f32_16x16x32_bf16(a0, b0, acc[0][0], 0, 0, 0);
    acc[0][1] = __builtin_amdgcn_mfma_f32_16x16x32_bf16(a0, b1, acc[0][1], 0, 0, 0);
    acc[1][0] = __builtin_amdgcn_mfma_f32_16x16x32_bf16(a1, b0, acc[1][0], 0, 0, 0);
    acc[1][1] = __builtin_amdgcn_mfma_f32_16x16x32_bf16(a1, b1, acc[1][1], 0, 0, 0);
  }

  float bj[2] = { bias[n0 + nw + ln], bias[n0 + nw + 16 + ln] };
#pragma unroll
  for (int i = 0; i < 2; ++i)
#pragma unroll
    for (int j = 0; j < 2; ++j) {
      const int nc = n0 + nw + 16 * j + ln;
#pragma unroll
      for (int r = 0; r < 4; ++r) {
        const int row = m0 + mw + 16 * i + quad * 4 + r;
        const size_t idx = (size_t)row * D_ + nc;
        float v = acc[i][j][r] + bj[j];
        g_h[idx] = v;
        g_hbf[idx] = f2bf(v);
      }
    }
}

__global__ __launch_bounds__(256) void k_pre(const float* __restrict__ x,
                                             const float* __restrict__ w_in,
                                             const float* __restrict__ b_in,
                                             const float* __restrict__ w1,
                                             const float* __restrict__ w2,
                                             const float* __restrict__ xp1,
                                             const float* __restrict__ xp2) {
  const int bx = blockIdx.x;
  if (bx < 512) { in_mfma_part(bx, x, w_in, b_in); return; }
  if (bx == 1088) {                 // zero mean accumulator + counters
#pragma unroll
    for (int j = 0; j < 8; ++j) g_mean[threadIdx.x * 8 + j] = 0.0f;
    if (threadIdx.x < 8) g_cntA[threadIdx.x] = 0;
    if (threadIdx.x == 8) g_cntm = 0;
    return;
  }
  int i = ((bx - 512) * 256 + threadIdx.x) * 4;
  const float* src; ushort_t* dst; int off;
  if (i < 262144)      { src = w1;  dst = g_w1bf;  off = i; }
  else if (i < 524288) { src = w2;  dst = g_w2bf;  off = i - 262144; }
  else if (i < 557056) { src = xp1; dst = g_xp1bf; off = i - 524288; }
  else                 { src = xp2; dst = g_xp2bf; off = i - 557056; }
  float4 v = *(const float4*)&src[off];
  ushort4 o; o.x = f2bf(v.x); o.y = f2bf(v.y); o.z = f2bf(v.z); o.w = f2bf(v.w);
  *(ushort4*)&dst[off] = o;
}

// ---------------------------------------------------------------------------
// bf16 MFMA GEMM (K=512), 64x64 tile, 4 waves, 2x2 16x16x32 MFMA per wave.
// DUAL: also store bf16. MEAN: col sums into g_mean.
// ---------------------------------------------------------------------------
template<bool DUAL, bool MEAN>
__device__ __forceinline__ void gemm_bf16_dev(
    const ushort_t* __restrict__ Abf, const ushort_t* __restrict__ Wbf,
    const float* __restrict__ bias, const float* __restrict__ res,
    float* __restrict__ out, ushort_t* __restrict__ obf) {
  __shared__ ushort_t As[64][72];
  __shared__ ushort_t Bs[64][72];
  const int tid  = threadIdx.x;
  const int m0   = (blockIdx.x >> 3) * 64;
  const int n0   = (blockIdx.x & 7) * 64;
  const int lane = tid & 63;
  const int wv   = tid >> 6;
  const int quad = lane >> 4;
  const int ln   = lane & 15;
  const int mw   = (wv & 1) * 32;
  const int nw   = (wv >> 1) * 32;

  f4_t acc[2][2] = {};

  for (int k0 = 0; k0 < 512; k0 += 64) {
#pragma unroll
    for (int c = 0; c < 2; ++c) {
      int idx = tid + c * 256;                 // 512 chunks of 8 bf16
      int m = idx >> 3, kq = (idx & 7) << 3;
      *(float4*)&As[m][kq] = *(const float4*)&Abf[(size_t)(m0 + m) * 512 + k0 + kq];
      *(float4*)&Bs[m][kq] = *(const float4*)&Wbf[(size_t)(n0 + m) * 512 + k0 + kq];
    }
    __syncthreads();
#pragma unroll
    for (int k1 = 0; k1 < 64; k1 += 32) {
      bf8_t a0 = *(const bf8_t*)&As[mw +      ln][k1 + quad * 8];
      bf8_t a1 = *(const bf8_t*)&As[mw + 16 + ln][k1 + quad * 8];
      bf8_t b0 = *(const bf8_t*)&Bs[nw +      ln][k1 + quad * 8];
      bf8_t b1 = *(const bf8_t*)&Bs[nw + 16 + ln][k1 + quad * 8];
      acc[0][0] = __builtin_amdgcn_mfma_f32_16x16x32_bf16(a0, b0, acc[0][0], 0, 0, 0);
      acc[0][1] = __builtin_amdgcn_mfma_f32_16x16x32_bf16(a0, b1, acc[0][1], 0, 0, 0);
      acc[1][0] = __builtin_amdgcn_mfma_f32_16x16x32_bf16(a1, b0, acc[1][0], 0, 0, 0);
      acc[1][1] = __builtin_amdgcn_mfma_f32_16x16x32_bf16(a1, b1, acc[1][1], 0, 0, 0);
    }
    __syncthreads();
  }

  float bj[2] = { bias[n0 + nw + ln], bias[n0 + nw + 16 + ln] };
  float psum[2][2] = {{0.f, 0.f}, {0.f, 0.f}};
#pragma unroll
  for (int i = 0; i < 2; ++i)
#pragma unroll
    for (int j = 0; j < 2; ++j) {
      const int nc = n0 + nw + 16 * j + ln;
#pragma unroll
      for (int r = 0; r < 4; ++r) {
        const int row = m0 + mw + 16 * i + quad * 4 + r;
        const size_t idx = (size_t)row * D_ + nc;
        float v = acc[i][j][r] + bj[j] + res[idx];
        out[idx] = v;
        if constexpr (DUAL) obf[idx] = f2bf(v);
        if constexpr (MEAN) psum[i][j] += v;
      }
    }
  if constexpr (MEAN) {
    __shared__ float ssum[16][64];
#pragma unroll
    for (int i = 0; i < 2; ++i)
#pragma unroll
      for (int j = 0; j < 2; ++j) {
        const int rg = (wv & 1) * 8 + i * 4 + quad;
        const int cl = (wv >> 1) * 32 + j * 16 + ln;
        ssum[rg][cl] = psum[i][j];
      }
    __syncthreads();
    if (tid < 64) {
      float s = 0.f;
#pragma unroll
      for (int rg = 0; rg < 16; ++rg) s += ssum[rg][tid];
      const int b = m0 >> 10;
      atomicAdd(&g_mean[b * D_ + n0 + tid], s);
    }
  }
}

__global__ __launch_bounds__(256) void k_mix1g(const float* __restrict__ bias) {
  gemm_bf16_dev<true, false>(g_gelubf, g_w1bf, bias, g_h, g_h2, g_hbf);
}

// mix2 + fused head (tail-block: mean-normalize + out-proj; tiny work)
__global__ __launch_bounds__(256) void k_mix2g(const float* __restrict__ bias,
                                               const float* __restrict__ out_w,
                                               const float* __restrict__ out_b,
                                               float* __restrict__ outp) {
  gemm_bf16_dev<false, true>(g_gelubf, g_w2bf, bias, g_h2, g_h, nullptr);

  __threadfence();                       // release: g_mean atomics done
  __shared__ int lastm;
  if (threadIdx.x == 0) lastm = (atomicAdd(&g_cntm, 1) == 511) ? 1 : 0;
  __syncthreads();
  if (!lastm) return;
  __threadfence();                       // acquire

  const int tid = threadIdx.x;
  __shared__ float smean[4][D_];
  __shared__ float sp[4][DOUT_][16];
  for (int i = tid; i < B_ * D_; i += 256)
    smean[i >> 9][i & 511] = g_mean[i] * (1.0f / L_);
  __syncthreads();
#pragma unroll
  for (int b = 0; b < B_; ++b)
    if (tid < DOUT_ * 16) {
      int o = tid >> 4, seg = tid & 15;
      float p = 0.0f;
#pragma unroll
      for (int i = 0; i < 32; ++i)
        p += smean[b][seg * 32 + i] * out_w[o * D_ + seg * 32 + i];
      sp[b][o][seg] = p;
    }
  __syncthreads();
  if (tid < B_ * DOUT_) {
    int b = tid / DOUT_, o = tid % DOUT_;
    float v = out_b[o];
#pragma unroll
    for (int j = 0; j < 16; ++j) v += sp[b][o][j];
    outp[b * DOUT_ + o] = v;
  }
}

// ---------------------------------------------------------------------------
// Per-layer kernel, decoupled-lookback (NO grid.sync — it costs ~100 µs).
// 256 blocks x 512 thr; LDS ~21 KB and VGPR<=128 so 2 blocks/CU always fit
// -> all 256 blocks resident -> spin gate cannot deadlock.
//   A: stage hbf rows to LDS; xdbl MFMA (B-frag direct from global xproj)
//      -> sx (LDS, persists); delta-proj + local scan -> stL/sumd; fence;
//      per-batch counter++ (release).
//   gate (c>0): tid0 acquire-polls counter==64 with s_sleep.
//   lookback: each block computes its OWN carry-in (forward recurrence j<c).
//   C: recompute delta from sx, seeded re-scan, emit bf16(gelu(y)).
// ---------------------------------------------------------------------------
__device__ __forceinline__ void load_A(const float* __restrict__ Alog, int d,
                                       float* A) {
#pragma unroll
  for (int n = 0; n < 16; n += 4) {
    float4 t = *(const float4*)&Alog[d * N_ + n];
    A[n + 0] = -__expf(t.x); A[n + 1] = -__expf(t.y);
    A[n + 2] = -__expf(t.z); A[n + 3] = -__expf(t.w);
  }
}

__device__ __forceinline__ void layer_dev(const float* __restrict__ h,
                                          const ushort_t* __restrict__ xpbf,
                                          const float* __restrict__ dtw,
                                          const float* __restrict__ dtb,
                                          const float* __restrict__ Alog,
                                          const float* __restrict__ Dp,
                                          ushort_t* __restrict__ ybf,
                                          int* __restrict__ cntA) {
  __shared__ ushort_t As[16][520];   // hbf tile (16 x 512, +8 pad)
  __shared__ float    sx[16][65];    // xdbl tile fp32 (dt|B|C) — persists
  const int tid  = threadIdx.x;      // 0..511
  const int c    = blockIdx.x & (CN_ - 1);
  const int b    = blockIdx.x >> 6;
  const int row0 = b * L_ + c * CL_;
  const int lane = tid & 63;
  const int wv   = tid >> 6;
  const int quad = lane >> 4;
  const int ln   = lane & 15;
  const int d    = tid;

  // stage hbf tile (16 x 512 bf16): 1024 16B chunks, 2/thread
#pragma unroll
  for (int i = 0; i < 2; ++i) {
    int idx = tid + i * 512;
    int m = idx >> 6, kq = (idx & 63) << 3;
    *(float4*)&As[m][kq] = *(const float4*)&g_hbf[(size_t)(row0 + m) * 512 + kq];
  }
  // per-thread params (live whole kernel; ~80 VGPR total, no spill at <=128)
  float w[32];
#pragma unroll
  for (int r = 0; r < 32; r += 4) {
    float4 t = *(const float4*)&dtw[d * R_ + r];
    w[r] = t.x; w[r + 1] = t.y; w[r + 2] = t.z; w[r + 3] = t.w;
  }
  const float bias = dtb[d];
  float A[16];
  load_A(Alog, d, A);
  const float Dpv = Dp[d];
  __syncthreads();

  // xdbl MFMA: waves 0..3 produce cols 16*wv..16*wv+15; B-frag from global
  if (wv < 4) {
    f4_t acc = {};
#pragma unroll
    for (int k0 = 0; k0 < 512; k0 += 32) {
      bf8_t a  = *(const bf8_t*)&As[ln][k0 + quad * 8];
      bf8_t bb = *(const bf8_t*)&xpbf[(size_t)(wv * 16 + ln) * 512 + k0 + quad * 8];
      acc = __builtin_amdgcn_mfma_f32_16x16x32_bf16(a, bb, acc, 0, 0, 0);
    }
#pragma unroll
    for (int r = 0; r < 4; ++r)
      sx[quad * 4 + r][wv * 16 + ln] = acc[r];
  }
  __syncthreads();

  // ---- phase A: delta-proj + local scan from 0 ----
  float st[16] = {};
  {
    float sumd = 0.0f;
#pragma unroll
    for (int l = 0; l < CL_; ++l) {
      float acc2 = bias;
#pragma unroll
      for (int k = 0; k < 32; ++k) acc2 = fmaf(sx[l][k], w[k], acc2);
      const float delta = softplus_f(acc2);
      const float dh = delta * h[(size_t)(row0 + l) * D_ + d];
      sumd += delta;
#pragma unroll
      for (int n = 0; n < 16; ++n) {
        float dA = __expf(delta * A[n]);
        st[n] = fmaf(dA, st[n], dh * sx[l][32 + n]);
      }
    }
    const size_t o = ((size_t)(b * CN_ + c) * D_ + d) * N_;
#pragma unroll
    for (int n = 0; n < 16; n += 4)
      *(float4*)&g_stL[o + n] = make_float4(st[n], st[n+1], st[n+2], st[n+3]);
    g_sumd[(b * CN_ + c) * D_ + d] = sumd;
  }
  __threadfence();                      // release stL/sumd (R8-validated pattern)
  __syncthreads();
  if (tid == 0)
    __hip_atomic_fetch_add(&cntA[b], 1, __ATOMIC_RELEASE, __HIP_MEMORY_SCOPE_AGENT);

  // ---- lookback: compute own carry-in (chunks j < c) ----
#pragma unroll
  for (int n = 0; n < 16; ++n) st[n] = 0.0f;
  if (c > 0) {
    if (tid == 0) {
      while (__hip_atomic_load(&cntA[b], __ATOMIC_ACQUIRE,
                               __HIP_MEMORY_SCOPE_AGENT) < CN_)
        __builtin_amdgcn_s_sleep(1);
    }
    __syncthreads();
    __threadfence();                    // acquire-side fence before data reads
#pragma unroll 2
    for (int j = 0; j < c; ++j) {
      const size_t base = ((size_t)(b * CN_ + j) * D_ + d) * N_;
      float sj[16];
      *(float4*)&sj[0]  = *(const float4*)&g_stL[base + 0];
      *(float4*)&sj[4]  = *(const float4*)&g_stL[base + 4];
      *(float4*)&sj[8]  = *(const float4*)&g_stL[base + 8];
      *(float4*)&sj[12] = *(const float4*)&g_stL[base + 12];
      const float pj = g_sumd[(b * CN_ + j) * D_ + d];
#pragma unroll
      for (int n = 0; n < 16; ++n)
        st[n] = fmaf(__expf(A[n] * pj), st[n], sj[n]);
    }
  }

  // ---- phase C: recompute delta from sx, seeded re-scan, emit ----
#pragma unroll
  for (int l = 0; l < CL_; ++l) {
    float acc2 = bias;
#pragma unroll
    for (int k = 0; k < 32; ++k) acc2 = fmaf(sx[l][k], w[k], acc2);
    const float delta = softplus_f(acc2);    // bit-identical to phase A
    const float hv = h[(size_t)(row0 + l) * D_ + d];
    const float dh = delta * hv;
    float y = 0.0f;
#pragma unroll
    for (int n = 0; n < 16; ++n) {
      float dA = __expf(delta * A[n]);
      st[n] = fmaf(dA, st[n], dh * sx[l][32 + n]);
      y = fmaf(st[n], sx[l][48 + n], y);
    }
    ybf[(size_t)(row0 + l) * D_ + d] = f2bf(gelu_f(y + hv * Dpv));
  }
}

__global__ __launch_bounds__(512, 4) void k_layer1(const float* dtw, const float* dtb,
                                                   const float* Alog, const float* Dp) {
  layer_dev(g_h, g_xp1bf, dtw, dtb, Alog, Dp, g_gelubf, &g_cntA[0]);
}
__global__ __launch_bounds__(512, 4) void k_layer2(const float* dtw, const float* dtb,
                                                   const float* Alog, const float* Dp) {
  layer_dev(g_h2, g_xp2bf, dtw, dtb, Alog, Dp, g_gelubf, &g_cntA[4]);
}

extern "C" void kernel_launch(void* const* d_in, const int* in_sizes, int n_in,
                              void* d_out, int out_size, void* d_ws, size_t ws_size,
                              hipStream_t stream) {
  const float* x        = (const float*)d_in[0];
  const float* W_in     = (const float*)d_in[1];
  const float* b_in     = (const float*)d_in[2];
  const float* mix1_w   = (const float*)d_in[3];
  const float* mix1_b   = (const float*)d_in[4];
  const float* mix2_w   = (const float*)d_in[5];
  const float* mix2_b   = (const float*)d_in[6];
  const float* out_w    = (const float*)d_in[7];
  const float* out_b    = (const float*)d_in[8];
  const float* m1_xproj = (const float*)d_in[9];
  const float* m1_dtw   = (const float*)d_in[10];
  const float* m1_dtb   = (const float*)d_in[11];
  const float* m1_Alog  = (const float*)d_in[12];
  const float* m1_D     = (const float*)d_in[13];
  const float* m2_xproj = (const float*)d_in[14];
  const float* m2_dtw   = (const float*)d_in[15];
  const float* m2_dtb   = (const float*)d_in[16];
  const float* m2_Alog  = (const float*)d_in[17];
  const float* m2_D     = (const float*)d_in[18];
  float* out = (float*)d_out;

  const int gScan = B_ * CN_;                // 256
  const int gMix  = (M_ / 64) * (D_ / 64);   // 512

  k_pre<<<1089, 256, 0, stream>>>(x, W_in, b_in, mix1_w, mix2_w, m1_xproj, m2_xproj);

  // ---- layer 1 ----
  k_layer1<<<gScan, 512, 0, stream>>>(m1_dtw, m1_dtb, m1_Alog, m1_D);
  k_mix1g <<<gMix,  256, 0, stream>>>(mix1_b);
  // ---- layer 2 ----
  k_layer2<<<gScan, 512, 0, stream>>>(m2_dtw, m2_dtb, m2_Alog, m2_D);
  k_mix2g <<<gMix,  256, 0, stream>>>(mix2_b, out_w, out_b, out);
}

// Round 11
// 286.486 us; speedup vs baseline: 2.3219x; 1.9064x over previous
//
#include <hip/hip_runtime.h>
#include <math.h>

typedef unsigned short ushort_t;
typedef short bf8_t __attribute__((ext_vector_type(8)));   // 8 bf16 in 4 VGPRs
typedef float f4_t  __attribute__((ext_vector_type(4)));

// Problem dims
constexpr int B_   = 4;
constexpr int L_   = 1024;
constexpr int DIN_ = 64;
constexpr int DOUT_= 10;
constexpr int D_   = 512;
constexpr int N_   = 16;
constexpr int R_   = 32;
constexpr int RN_  = 64;          // R + 2N
constexpr int M_   = B_ * L_;     // 4096 rows (b,l) flattened

// Chunked scan config
constexpr int CN_ = 64;           // chunks over L
constexpr int CL_ = L_ / CN_;     // 16 steps per chunk

// Intermediates (device globals; referenced ONLY inside device code).
__device__ float    g_h   [M_ * D_];    // hidden fp32 (layer-1 input / residual)
__device__ float    g_h2  [M_ * D_];    // hidden fp32 (layer-2 input / residual)
__device__ ushort_t g_hbf [M_ * D_];    // bf16 copy of current hidden
__device__ ushort_t g_gelubf[M_ * D_];  // bf16(gelu(mamba_y)) (mix A-operand)
__device__ float    g_stL  [B_ * CN_ * D_ * N_];
__device__ float    g_sumd [B_ * CN_ * D_];
__device__ float    g_carry[B_ * CN_ * D_ * N_];
__device__ float    g_mean [B_ * D_];   // column sums of final hidden (atomics)
__device__ int      g_cntm;             // mix2 tail counter
// bf16 weights (re-converted each call)
__device__ ushort_t g_w1bf [D_ * D_];
__device__ ushort_t g_w2bf [D_ * D_];
__device__ ushort_t g_xp1bf[RN_ * D_];
__device__ ushort_t g_xp2bf[RN_ * D_];

__device__ __forceinline__ float gelu_f(float x) {
  return 0.5f * x * (1.0f + erff(x * 0.7071067811865475f));
}
__device__ __forceinline__ float softplus_f(float x) {
  return fmaxf(x, 0.0f) + log1pf(__expf(-fabsf(x)));
}
__device__ __forceinline__ ushort_t f2bf(float x) {  // RNE fp32->bf16
  union { float f; unsigned u; } v; v.f = x;
  unsigned r = v.u + 0x7fffu + ((v.u >> 16) & 1u);
  return (ushort_t)(r >> 16);
}

// ---------------------------------------------------------------------------
// k_pre: blocks [0,512)   = in-projection bf16 MFMA (x @ W_in^T + b)
//        blocks [512,1088)= weight fp32->bf16 conversion
//        block  1088      = zero g_mean + counter
// ---------------------------------------------------------------------------
__device__ __forceinline__ void in_mfma_part(int bx,
                                             const float* __restrict__ x,
                                             const float* __restrict__ w,
                                             const float* __restrict__ bias) {
  __shared__ ushort_t As[64][72];
  __shared__ ushort_t Bs[64][72];
  const int tid  = threadIdx.x;
  const int m0   = (bx >> 3) * 64;
  const int n0   = (bx & 7) * 64;
  const int lane = tid & 63;
  const int wv   = tid >> 6;
  const int quad = lane >> 4;
  const int ln   = lane & 15;
  const int mw   = (wv & 1) * 32;
  const int nw   = (wv >> 1) * 32;

  {
    const int m = tid >> 2, q = (tid & 3) << 4;
#pragma unroll
    for (int i = 0; i < 4; ++i) {
      float4 va = *(const float4*)&x[(size_t)(m0 + m) * 64 + q + i * 4];
      float4 vb = *(const float4*)&w[(size_t)(n0 + m) * 64 + q + i * 4];
      ushort4 oa, ob;
      oa.x = f2bf(va.x); oa.y = f2bf(va.y); oa.z = f2bf(va.z); oa.w = f2bf(va.w);
      ob.x = f2bf(vb.x); ob.y = f2bf(vb.y); ob.z = f2bf(vb.z); ob.w = f2bf(vb.w);
      *(ushort4*)&As[m][q + i * 4] = oa;
      *(ushort4*)&Bs[m][q + i * 4] = ob;
    }
  }
  __syncthreads();

  f4_t acc[2][2] = {};
#pragma unroll
  for (int k1 = 0; k1 < 64; k1 += 32) {
    bf8_t a0 = *(const bf8_t*)&As[mw +      ln][k1 + quad * 8];
    bf8_t a1 = *(const bf8_t*)&As[mw + 16 + ln][k1 + quad * 8];
    bf8_t b0 = *(const bf8_t*)&Bs[nw +      ln][k1 + quad * 8];
    bf8_t b1 = *(const bf8_t*)&Bs[nw + 16 + ln][k1 + quad * 8];
    acc[0][0] = __builtin_amdgcn_mfma_f32_16x16x32_bf16(a0, b0, acc[0][0], 0, 0, 0);
    acc[0][1] = __builtin_amdgcn_mfma_f32_16x16x32_bf16(a0, b1, acc[0][1], 0, 0, 0);
    acc[1][0] = __builtin_amdgcn_mfma_f32_16x16x32_bf16(a1, b0, acc[1][0], 0, 0, 0);
    acc[1][1] = __builtin_amdgcn_mfma_f32_16x16x32_bf16(a1, b1, acc[1][1], 0, 0, 0);
  }

  float bj[2] = { bias[n0 + nw + ln], bias[n0 + nw + 16 + ln] };
#pragma unroll
  for (int i = 0; i < 2; ++i)
#pragma unroll
    for (int j = 0; j < 2; ++j) {
      const int nc = n0 + nw + 16 * j + ln;
#pragma unroll
      for (int r = 0; r < 4; ++r) {
        const int row = m0 + mw + 16 * i + quad * 4 + r;
        const size_t idx = (size_t)row * D_ + nc;
        float v = acc[i][j][r] + bj[j];
        g_h[idx] = v;
        g_hbf[idx] = f2bf(v);
      }
    }
}

__global__ __launch_bounds__(256) void k_pre(const float* __restrict__ x,
                                             const float* __restrict__ w_in,
                                             const float* __restrict__ b_in,
                                             const float* __restrict__ w1,
                                             const float* __restrict__ w2,
                                             const float* __restrict__ xp1,
                                             const float* __restrict__ xp2) {
  const int bx = blockIdx.x;
  if (bx < 512) { in_mfma_part(bx, x, w_in, b_in); return; }
  if (bx == 1088) {                 // zero mean accumulator + counter
#pragma unroll
    for (int j = 0; j < 8; ++j) g_mean[threadIdx.x * 8 + j] = 0.0f;
    if (threadIdx.x == 0) g_cntm = 0;
    return;
  }
  int i = ((bx - 512) * 256 + threadIdx.x) * 4;
  const float* src; ushort_t* dst; int off;
  if (i < 262144)      { src = w1;  dst = g_w1bf;  off = i; }
  else if (i < 524288) { src = w2;  dst = g_w2bf;  off = i - 262144; }
  else if (i < 557056) { src = xp1; dst = g_xp1bf; off = i - 524288; }
  else                 { src = xp2; dst = g_xp2bf; off = i - 557056; }
  float4 v = *(const float4*)&src[off];
  ushort4 o; o.x = f2bf(v.x); o.y = f2bf(v.y); o.z = f2bf(v.z); o.w = f2bf(v.w);
  *(ushort4*)&dst[off] = o;
}

// ---------------------------------------------------------------------------
// bf16 MFMA GEMM (K=512), 64x64 tile, 4 waves, 2x2 16x16x32 MFMA per wave.
// DUAL: also store bf16. MEAN: col sums into g_mean.
// ---------------------------------------------------------------------------
template<bool DUAL, bool MEAN>
__device__ __forceinline__ void gemm_bf16_dev(
    const ushort_t* __restrict__ Abf, const ushort_t* __restrict__ Wbf,
    const float* __restrict__ bias, const float* __restrict__ res,
    float* __restrict__ out, ushort_t* __restrict__ obf) {
  __shared__ ushort_t As[64][72];
  __shared__ ushort_t Bs[64][72];
  const int tid  = threadIdx.x;
  const int m0   = (blockIdx.x >> 3) * 64;
  const int n0   = (blockIdx.x & 7) * 64;
  const int lane = tid & 63;
  const int wv   = tid >> 6;
  const int quad = lane >> 4;
  const int ln   = lane & 15;
  const int mw   = (wv & 1) * 32;
  const int nw   = (wv >> 1) * 32;

  f4_t acc[2][2] = {};

  for (int k0 = 0; k0 < 512; k0 += 64) {
#pragma unroll
    for (int c = 0; c < 2; ++c) {
      int idx = tid + c * 256;                 // 512 chunks of 8 bf16
      int m = idx >> 3, kq = (idx & 7) << 3;
      *(float4*)&As[m][kq] = *(const float4*)&Abf[(size_t)(m0 + m) * 512 + k0 + kq];
      *(float4*)&Bs[m][kq] = *(const float4*)&Wbf[(size_t)(n0 + m) * 512 + k0 + kq];
    }
    __syncthreads();
#pragma unroll
    for (int k1 = 0; k1 < 64; k1 += 32) {
      bf8_t a0 = *(const bf8_t*)&As[mw +      ln][k1 + quad * 8];
      bf8_t a1 = *(const bf8_t*)&As[mw + 16 + ln][k1 + quad * 8];
      bf8_t b0 = *(const bf8_t*)&Bs[nw +      ln][k1 + quad * 8];
      bf8_t b1 = *(const bf8_t*)&Bs[nw + 16 + ln][k1 + quad * 8];
      acc[0][0] = __builtin_amdgcn_mfma_f32_16x16x32_bf16(a0, b0, acc[0][0], 0, 0, 0);
      acc[0][1] = __builtin_amdgcn_mfma_f32_16x16x32_bf16(a0, b1, acc[0][1], 0, 0, 0);
      acc[1][0] = __builtin_amdgcn_mfma_f32_16x16x32_bf16(a1, b0, acc[1][0], 0, 0, 0);
      acc[1][1] = __builtin_amdgcn_mfma_f32_16x16x32_bf16(a1, b1, acc[1][1], 0, 0, 0);
    }
    __syncthreads();
  }

  float bj[2] = { bias[n0 + nw + ln], bias[n0 + nw + 16 + ln] };
  float psum[2][2] = {{0.f, 0.f}, {0.f, 0.f}};
#pragma unroll
  for (int i = 0; i < 2; ++i)
#pragma unroll
    for (int j = 0; j < 2; ++j) {
      const int nc = n0 + nw + 16 * j + ln;
#pragma unroll
      for (int r = 0; r < 4; ++r) {
        const int row = m0 + mw + 16 * i + quad * 4 + r;
        const size_t idx = (size_t)row * D_ + nc;
        float v = acc[i][j][r] + bj[j] + res[idx];
        out[idx] = v;
        if constexpr (DUAL) obf[idx] = f2bf(v);
        if constexpr (MEAN) psum[i][j] += v;
      }
    }
  if constexpr (MEAN) {
    __shared__ float ssum[16][64];
#pragma unroll
    for (int i = 0; i < 2; ++i)
#pragma unroll
      for (int j = 0; j < 2; ++j) {
        const int rg = (wv & 1) * 8 + i * 4 + quad;
        const int cl = (wv >> 1) * 32 + j * 16 + ln;
        ssum[rg][cl] = psum[i][j];
      }
    __syncthreads();
    if (tid < 64) {
      float s = 0.f;
#pragma unroll
      for (int rg = 0; rg < 16; ++rg) s += ssum[rg][tid];
      const int b = m0 >> 10;
      atomicAdd(&g_mean[b * D_ + n0 + tid], s);
    }
  }
}

__global__ __launch_bounds__(256) void k_mix1g(const float* __restrict__ bias) {
  gemm_bf16_dev<true, false>(g_gelubf, g_w1bf, bias, g_h, g_h2, g_hbf);
}

// mix2 + fused head (tail-block: mean-normalize + out-proj; tiny work)
__global__ __launch_bounds__(256) void k_mix2g(const float* __restrict__ bias,
                                               const float* __restrict__ out_w,
                                               const float* __restrict__ out_b,
                                               float* __restrict__ outp) {
  gemm_bf16_dev<false, true>(g_gelubf, g_w2bf, bias, g_h2, g_h, nullptr);

  __threadfence();                       // release: g_mean atomics done
  __shared__ int lastm;
  if (threadIdx.x == 0) lastm = (atomicAdd(&g_cntm, 1) == 511) ? 1 : 0;
  __syncthreads();
  if (!lastm) return;
  __threadfence();                       // acquire

  const int tid = threadIdx.x;
  __shared__ float smean[4][D_];
  __shared__ float sp[4][DOUT_][16];
  for (int i = tid; i < B_ * D_; i += 256)
    smean[i >> 9][i & 511] = g_mean[i] * (1.0f / L_);
  __syncthreads();
#pragma unroll
  for (int b = 0; b < B_; ++b)
    if (tid < DOUT_ * 16) {
      int o = tid >> 4, seg = tid & 15;
      float p = 0.0f;
#pragma unroll
      for (int i = 0; i < 32; ++i)
        p += smean[b][seg * 32 + i] * out_w[o * D_ + seg * 32 + i];
      sp[b][o][seg] = p;
    }
  __syncthreads();
  if (tid < B_ * DOUT_) {
    int b = tid / DOUT_, o = tid % DOUT_;
    float v = out_b[o];
#pragma unroll
    for (int j = 0; j < 16; ++j) v += sp[b][o][j];
    outp[b * DOUT_ + o] = v;
  }
}

// ---------------------------------------------------------------------------
// Shared piece: stage hbf chunk-tile to LDS, run fused xdbl MFMA into sx.
// B-fragments read directly from global xproj (64 KB, L2-resident).
// sx[l][0:32)=dt, [32:48)=B, [48:64)=C.  Bench-verified in R8/R9/R10.
// ---------------------------------------------------------------------------
__device__ __forceinline__ void load_A(const float* __restrict__ Alog, int d,
                                       float* A) {
#pragma unroll
  for (int n = 0; n < 16; n += 4) {
    float4 t = *(const float4*)&Alog[d * N_ + n];
    A[n + 0] = -__expf(t.x); A[n + 1] = -__expf(t.y);
    A[n + 2] = -__expf(t.z); A[n + 3] = -__expf(t.w);
  }
}

__device__ __forceinline__ void xdbl_tile(const ushort_t* __restrict__ xpbf,
                                          int row0, int tid,
                                          ushort_t (*As)[520], float (*sx)[65]) {
  const int lane = tid & 63;
  const int wv   = tid >> 6;
  const int quad = lane >> 4;
  const int ln   = lane & 15;
#pragma unroll
  for (int i = 0; i < 2; ++i) {
    int idx = tid + i * 512;
    int m = idx >> 6, kq = (idx & 63) << 3;
    *(float4*)&As[m][kq] = *(const float4*)&g_hbf[(size_t)(row0 + m) * 512 + kq];
  }
  __syncthreads();
  if (wv < 4) {
    f4_t acc = {};
#pragma unroll
    for (int k0 = 0; k0 < 512; k0 += 32) {
      bf8_t a  = *(const bf8_t*)&As[ln][k0 + quad * 8];
      bf8_t bb = *(const bf8_t*)&xpbf[(size_t)(wv * 16 + ln) * 512 + k0 + quad * 8];
      acc = __builtin_amdgcn_mfma_f32_16x16x32_bf16(a, bb, acc, 0, 0, 0);
    }
#pragma unroll
    for (int r = 0; r < 4; ++r)
      sx[quad * 4 + r][wv * 16 + ln] = acc[r];
  }
  __syncthreads();
}

// ---------------------------------------------------------------------------
// p1f: fused xdbl + delta-proj + local scan from 0 -> stL/sumd. Pure kernel,
// no cross-block communication (per-CU-BW / fence lessons from R8/R10).
// ---------------------------------------------------------------------------
__device__ __forceinline__ void p1f_dev(const float* __restrict__ h,
                                        const ushort_t* __restrict__ xpbf,
                                        const float* __restrict__ dtw,
                                        const float* __restrict__ dtb,
                                        const float* __restrict__ Alog) {
  __shared__ ushort_t As[16][520];
  __shared__ float    sx[16][65];
  const int tid  = threadIdx.x;      // 0..511
  const int c    = blockIdx.x & (CN_ - 1);
  const int b    = blockIdx.x >> 6;
  const int row0 = b * L_ + c * CL_;
  const int d    = tid;

  float w[32];
#pragma unroll
  for (int r = 0; r < 32; r += 4) {
    float4 t = *(const float4*)&dtw[d * R_ + r];
    w[r] = t.x; w[r + 1] = t.y; w[r + 2] = t.z; w[r + 3] = t.w;
  }
  const float bias = dtb[d];
  float A[16];
  load_A(Alog, d, A);

  xdbl_tile(xpbf, row0, tid, As, sx);

  float st[16] = {};
  float sumd = 0.0f;
#pragma unroll
  for (int l = 0; l < CL_; ++l) {
    float acc2 = bias;
#pragma unroll
    for (int k = 0; k < 32; ++k) acc2 = fmaf(sx[l][k], w[k], acc2);
    const float delta = softplus_f(acc2);
    const float dh = delta * h[(size_t)(row0 + l) * D_ + d];
    sumd += delta;
#pragma unroll
    for (int n = 0; n < 16; ++n) {
      float dA = __expf(delta * A[n]);
      st[n] = fmaf(dA, st[n], dh * sx[l][32 + n]);
    }
  }
  const size_t o = ((size_t)(b * CN_ + c) * D_ + d) * N_;
#pragma unroll
  for (int n = 0; n < 16; n += 4)
    *(float4*)&g_stL[o + n] = make_float4(st[n], st[n+1], st[n+2], st[n+3]);
  g_sumd[(b * CN_ + c) * D_ + d] = sumd;
}

__global__ __launch_bounds__(512, 4) void k_p1f_1(const float* dtw, const float* dtb,
                                                  const float* Alog) {
  p1f_dev(g_h, g_xp1bf, dtw, dtb, Alog);
}
__global__ __launch_bounds__(512, 4) void k_p1f_2(const float* dtw, const float* dtb,
                                                  const float* Alog) {
  p1f_dev(g_h2, g_xp2bf, dtw, dtb, Alog);
}

// ---------------------------------------------------------------------------
// carry: H_c = exp(A*sumd_c) * H_{c-1} + S_c; 1 thread per (b,d,n) chain,
// 16-wide prefetch. Full-grid parallelism (R7-proven fast).
// ---------------------------------------------------------------------------
__global__ __launch_bounds__(256) void k_scan_carry(const float* __restrict__ Alog) {
  const int g = blockIdx.x * 256 + threadIdx.x;     // B*D*N = 32768 threads
  const int n = g & 15;
  const int d = (g >> 4) & (D_ - 1);
  const int b = g >> 13;
  const float A = -__expf(Alog[d * N_ + n]);
  float carry = 0.0f;
#pragma unroll
  for (int c0 = 0; c0 < CN_; c0 += 16) {
    float s[16], p[16];
#pragma unroll
    for (int j = 0; j < 16; ++j) {
      s[j] = g_stL[((size_t)(b * CN_ + c0 + j) * D_ + d) * N_ + n];
      p[j] = g_sumd[(b * CN_ + c0 + j) * D_ + d];
    }
#pragma unroll
    for (int j = 0; j < 16; ++j) {
      g_carry[((size_t)(b * CN_ + c0 + j) * D_ + d) * N_ + n] = carry;
      carry = fmaf(__expf(A * p[j]), carry, s[j]);
    }
  }
}

// ---------------------------------------------------------------------------
// p2f: fused xdbl (recomputed, bit-identical) + carry-seeded re-scan + emit.
// ---------------------------------------------------------------------------
__device__ __forceinline__ void p2f_dev(const float* __restrict__ h,
                                        const ushort_t* __restrict__ xpbf,
                                        const float* __restrict__ dtw,
                                        const float* __restrict__ dtb,
                                        const float* __restrict__ Alog,
                                        const float* __restrict__ Dp,
                                        ushort_t* __restrict__ ybf) {
  __shared__ ushort_t As[16][520];
  __shared__ float    sx[16][65];
  const int tid  = threadIdx.x;
  const int c    = blockIdx.x & (CN_ - 1);
  const int b    = blockIdx.x >> 6;
  const int row0 = b * L_ + c * CL_;
  const int d    = tid;

  float w[32];
#pragma unroll
  for (int r = 0; r < 32; r += 4) {
    float4 t = *(const float4*)&dtw[d * R_ + r];
    w[r] = t.x; w[r + 1] = t.y; w[r + 2] = t.z; w[r + 3] = t.w;
  }
  const float bias = dtb[d];
  float A[16];
  load_A(Alog, d, A);
  const float Dpv = Dp[d];

  xdbl_tile(xpbf, row0, tid, As, sx);

  float st[16];
  const size_t o = ((size_t)(b * CN_ + c) * D_ + d) * N_;
#pragma unroll
  for (int n = 0; n < 16; n += 4) {
    float4 t = *(const float4*)&g_carry[o + n];
    st[n] = t.x; st[n+1] = t.y; st[n+2] = t.z; st[n+3] = t.w;
  }
#pragma unroll
  for (int l = 0; l < CL_; ++l) {
    float acc2 = bias;
#pragma unroll
    for (int k = 0; k < 32; ++k) acc2 = fmaf(sx[l][k], w[k], acc2);
    const float delta = softplus_f(acc2);     // bit-identical to p1f
    const float hv = h[(size_t)(row0 + l) * D_ + d];
    const float dh = delta * hv;
    float y = 0.0f;
#pragma unroll
    for (int n = 0; n < 16; ++n) {
      float dA = __expf(delta * A[n]);
      st[n] = fmaf(dA, st[n], dh * sx[l][32 + n]);
      y = fmaf(st[n], sx[l][48 + n], y);
    }
    ybf[(size_t)(row0 + l) * D_ + d] = f2bf(gelu_f(y + hv * Dpv));
  }
}

__global__ __launch_bounds__(512, 4) void k_p2f_1(const float* dtw, const float* dtb,
                                                  const float* Alog, const float* Dp) {
  p2f_dev(g_h, g_xp1bf, dtw, dtb, Alog, Dp, g_gelubf);
}
__global__ __launch_bounds__(512, 4) void k_p2f_2(const float* dtw, const float* dtb,
                                                  const float* Alog, const float* Dp) {
  p2f_dev(g_h2, g_xp2bf, dtw, dtb, Alog, Dp, g_gelubf);
}

extern "C" void kernel_launch(void* const* d_in, const int* in_sizes, int n_in,
                              void* d_out, int out_size, void* d_ws, size_t ws_size,
                              hipStream_t stream) {
  const float* x        = (const float*)d_in[0];
  const float* W_in     = (const float*)d_in[1];
  const float* b_in     = (const float*)d_in[2];
  const float* mix1_w   = (const float*)d_in[3];
  const float* mix1_b   = (const float*)d_in[4];
  const float* mix2_w   = (const float*)d_in[5];
  const float* mix2_b   = (const float*)d_in[6];
  const float* out_w    = (const float*)d_in[7];
  const float* out_b    = (const float*)d_in[8];
  const float* m1_xproj = (const float*)d_in[9];
  const float* m1_dtw   = (const float*)d_in[10];
  const float* m1_dtb   = (const float*)d_in[11];
  const float* m1_Alog  = (const float*)d_in[12];
  const float* m1_D     = (const float*)d_in[13];
  const float* m2_xproj = (const float*)d_in[14];
  const float* m2_dtw   = (const float*)d_in[15];
  const float* m2_dtb   = (const float*)d_in[16];
  const float* m2_Alog  = (const float*)d_in[17];
  const float* m2_D     = (const float*)d_in[18];
  float* out = (float*)d_out;

  const int gScan  = B_ * CN_;                // 256
  const int gCarry = (B_ * D_ * N_) / 256;    // 128
  const int gMix   = (M_ / 64) * (D_ / 64);   // 512

  k_pre<<<1089, 256, 0, stream>>>(x, W_in, b_in, mix1_w, mix2_w, m1_xproj, m2_xproj);

  // ---- layer 1 ----
  k_p1f_1     <<<gScan,  512, 0, stream>>>(m1_dtw, m1_dtb, m1_Alog);
  k_scan_carry<<<gCarry, 256, 0, stream>>>(m1_Alog);
  k_p2f_1     <<<gScan,  512, 0, stream>>>(m1_dtw, m1_dtb, m1_Alog, m1_D);
  k_mix1g     <<<gMix,   256, 0, stream>>>(mix1_b);
  // ---- layer 2 ----
  k_p1f_2     <<<gScan,  512, 0, stream>>>(m2_dtw, m2_dtb, m2_Alog);
  k_scan_carry<<<gCarry, 256, 0, stream>>>(m2_Alog);
  k_p2f_2     <<<gScan,  512, 0, stream>>>(m2_dtw, m2_dtb, m2_Alog, m2_D);
  k_mix2g     <<<gMix,   256, 0, stream>>>(mix2_b, out_w, out_b, out);
}

// Round 12
// 237.611 us; speedup vs baseline: 2.7995x; 1.2057x over previous
//
#include <hip/hip_runtime.h>
#include <math.h>

typedef unsigned short ushort_t;
typedef short bf8_t __attribute__((ext_vector_type(8)));   // 8 bf16 in 4 VGPRs
typedef float f4_t  __attribute__((ext_vector_type(4)));

// Problem dims
constexpr int B_   = 4;
constexpr int L_   = 1024;
constexpr int DIN_ = 64;
constexpr int DOUT_= 10;
constexpr int D_   = 512;
constexpr int N_   = 16;
constexpr int R_   = 32;
constexpr int RN_  = 64;          // R + 2N
constexpr int M_   = B_ * L_;     // 4096 rows (b,l) flattened

// Chunked scan config
constexpr int CN_ = 64;           // chunks over L
constexpr int CL_ = L_ / CN_;     // 16 steps per chunk

// Intermediates (device globals; referenced ONLY inside device code).
__device__ float    g_h   [M_ * D_];    // hidden fp32 (layer-1 input / residual)
__device__ float    g_h2  [M_ * D_];    // hidden fp32 (layer-2 input / residual)
__device__ ushort_t g_hbf [M_ * D_];    // bf16 copy of current hidden
__device__ ushort_t g_gelubf[M_ * D_];  // bf16(gelu(mamba_y)) (mix A-operand)
__device__ float    g_stL  [B_ * CN_ * D_ * N_];
__device__ float    g_sumd [B_ * CN_ * D_];
__device__ float    g_carry[B_ * CN_ * D_ * N_];
__device__ float    g_mean [B_ * D_];   // column sums of final hidden (atomics)
// bf16 weights (re-converted each call)
__device__ ushort_t g_w1bf [D_ * D_];
__device__ ushort_t g_w2bf [D_ * D_];
__device__ ushort_t g_xp1bf[RN_ * D_];
__device__ ushort_t g_xp2bf[RN_ * D_];

__device__ __forceinline__ float gelu_f(float x) {
  return 0.5f * x * (1.0f + erff(x * 0.7071067811865475f));
}
__device__ __forceinline__ float softplus_f(float x) {
  return fmaxf(x, 0.0f) + log1pf(__expf(-fabsf(x)));
}
__device__ __forceinline__ ushort_t f2bf(float x) {  // RNE fp32->bf16
  union { float f; unsigned u; } v; v.f = x;
  unsigned r = v.u + 0x7fffu + ((v.u >> 16) & 1u);
  return (ushort_t)(r >> 16);
}

// ---------------------------------------------------------------------------
// k_pre: blocks [0,512)   = in-projection bf16 MFMA (x @ W_in^T + b)
//        blocks [512,1088)= weight fp32->bf16 conversion
//        block  1088      = zero g_mean
// ---------------------------------------------------------------------------
__device__ __forceinline__ void in_mfma_part(int bx,
                                             const float* __restrict__ x,
                                             const float* __restrict__ w,
                                             const float* __restrict__ bias) {
  __shared__ ushort_t As[64][72];
  __shared__ ushort_t Bs[64][72];
  const int tid  = threadIdx.x;
  const int m0   = (bx >> 3) * 64;
  const int n0   = (bx & 7) * 64;
  const int lane = tid & 63;
  const int wv   = tid >> 6;
  const int quad = lane >> 4;
  const int ln   = lane & 15;
  const int mw   = (wv & 1) * 32;
  const int nw   = (wv >> 1) * 32;

  {
    const int m = tid >> 2, q = (tid & 3) << 4;
#pragma unroll
    for (int i = 0; i < 4; ++i) {
      float4 va = *(const float4*)&x[(size_t)(m0 + m) * 64 + q + i * 4];
      float4 vb = *(const float4*)&w[(size_t)(n0 + m) * 64 + q + i * 4];
      ushort4 oa, ob;
      oa.x = f2bf(va.x); oa.y = f2bf(va.y); oa.z = f2bf(va.z); oa.w = f2bf(va.w);
      ob.x = f2bf(vb.x); ob.y = f2bf(vb.y); ob.z = f2bf(vb.z); ob.w = f2bf(vb.w);
      *(ushort4*)&As[m][q + i * 4] = oa;
      *(ushort4*)&Bs[m][q + i * 4] = ob;
    }
  }
  __syncthreads();

  f4_t acc[2][2] = {};
#pragma unroll
  for (int k1 = 0; k1 < 64; k1 += 32) {
    bf8_t a0 = *(const bf8_t*)&As[mw +      ln][k1 + quad * 8];
    bf8_t a1 = *(const bf8_t*)&As[mw + 16 + ln][k1 + quad * 8];
    bf8_t b0 = *(const bf8_t*)&Bs[nw +      ln][k1 + quad * 8];
    bf8_t b1 = *(const bf8_t*)&Bs[nw + 16 + ln][k1 + quad * 8];
    acc[0][0] = __builtin_amdgcn_mfma_f32_16x16x32_bf16(a0, b0, acc[0][0], 0, 0, 0);
    acc[0][1] = __builtin_amdgcn_mfma_f32_16x16x32_bf16(a0, b1, acc[0][1], 0, 0, 0);
    acc[1][0] = __builtin_amdgcn_mfma_f32_16x16x32_bf16(a1, b0, acc[1][0], 0, 0, 0);
    acc[1][1] = __builtin_amdgcn_mfma_f32_16x16x32_bf16(a1, b1, acc[1][1], 0, 0, 0);
  }

  float bj[2] = { bias[n0 + nw + ln], bias[n0 + nw + 16 + ln] };
#pragma unroll
  for (int i = 0; i < 2; ++i)
#pragma unroll
    for (int j = 0; j < 2; ++j) {
      const int nc = n0 + nw + 16 * j + ln;
#pragma unroll
      for (int r = 0; r < 4; ++r) {
        const int row = m0 + mw + 16 * i + quad * 4 + r;
        const size_t idx = (size_t)row * D_ + nc;
        float v = acc[i][j][r] + bj[j];
        g_h[idx] = v;
        g_hbf[idx] = f2bf(v);
      }
    }
}

__global__ __launch_bounds__(256) void k_pre(const float* __restrict__ x,
                                             const float* __restrict__ w_in,
                                             const float* __restrict__ b_in,
                                             const float* __restrict__ w1,
                                             const float* __restrict__ w2,
                                             const float* __restrict__ xp1,
                                             const float* __restrict__ xp2) {
  const int bx = blockIdx.x;
  if (bx < 512) { in_mfma_part(bx, x, w_in, b_in); return; }
  if (bx == 1088) {                 // zero mean accumulator (B*D = 2048)
#pragma unroll
    for (int j = 0; j < 8; ++j) g_mean[threadIdx.x * 8 + j] = 0.0f;
    return;
  }
  int i = ((bx - 512) * 256 + threadIdx.x) * 4;
  const float* src; ushort_t* dst; int off;
  if (i < 262144)      { src = w1;  dst = g_w1bf;  off = i; }
  else if (i < 524288) { src = w2;  dst = g_w2bf;  off = i - 262144; }
  else if (i < 557056) { src = xp1; dst = g_xp1bf; off = i - 524288; }
  else                 { src = xp2; dst = g_xp2bf; off = i - 557056; }
  float4 v = *(const float4*)&src[off];
  ushort4 o; o.x = f2bf(v.x); o.y = f2bf(v.y); o.z = f2bf(v.z); o.w = f2bf(v.w);
  *(ushort4*)&dst[off] = o;
}

// ---------------------------------------------------------------------------
// bf16 MFMA GEMM (K=512), 64x64 tile, 4 waves, 2x2 16x16x32 MFMA per wave.
// DUAL: also store bf16. MEAN: col sums into g_mean (distributed atomics —
// measured harmless in R7; the fence+single-counter tail was the R11 poison).
// ---------------------------------------------------------------------------
template<bool DUAL, bool MEAN>
__device__ __forceinline__ void gemm_bf16_dev(
    const ushort_t* __restrict__ Abf, const ushort_t* __restrict__ Wbf,
    const float* __restrict__ bias, const float* __restrict__ res,
    float* __restrict__ out, ushort_t* __restrict__ obf) {
  __shared__ ushort_t As[64][72];
  __shared__ ushort_t Bs[64][72];
  const int tid  = threadIdx.x;
  const int m0   = (blockIdx.x >> 3) * 64;
  const int n0   = (blockIdx.x & 7) * 64;
  const int lane = tid & 63;
  const int wv   = tid >> 6;
  const int quad = lane >> 4;
  const int ln   = lane & 15;
  const int mw   = (wv & 1) * 32;
  const int nw   = (wv >> 1) * 32;

  f4_t acc[2][2] = {};

  for (int k0 = 0; k0 < 512; k0 += 64) {
#pragma unroll
    for (int c = 0; c < 2; ++c) {
      int idx = tid + c * 256;                 // 512 chunks of 8 bf16
      int m = idx >> 3, kq = (idx & 7) << 3;
      *(float4*)&As[m][kq] = *(const float4*)&Abf[(size_t)(m0 + m) * 512 + k0 + kq];
      *(float4*)&Bs[m][kq] = *(const float4*)&Wbf[(size_t)(n0 + m) * 512 + k0 + kq];
    }
    __syncthreads();
#pragma unroll
    for (int k1 = 0; k1 < 64; k1 += 32) {
      bf8_t a0 = *(const bf8_t*)&As[mw +      ln][k1 + quad * 8];
      bf8_t a1 = *(const bf8_t*)&As[mw + 16 + ln][k1 + quad * 8];
      bf8_t b0 = *(const bf8_t*)&Bs[nw +      ln][k1 + quad * 8];
      bf8_t b1 = *(const bf8_t*)&Bs[nw + 16 + ln][k1 + quad * 8];
      acc[0][0] = __builtin_amdgcn_mfma_f32_16x16x32_bf16(a0, b0, acc[0][0], 0, 0, 0);
      acc[0][1] = __builtin_amdgcn_mfma_f32_16x16x32_bf16(a0, b1, acc[0][1], 0, 0, 0);
      acc[1][0] = __builtin_amdgcn_mfma_f32_16x16x32_bf16(a1, b0, acc[1][0], 0, 0, 0);
      acc[1][1] = __builtin_amdgcn_mfma_f32_16x16x32_bf16(a1, b1, acc[1][1], 0, 0, 0);
    }
    __syncthreads();
  }

  float bj[2] = { bias[n0 + nw + ln], bias[n0 + nw + 16 + ln] };
  float psum[2][2] = {{0.f, 0.f}, {0.f, 0.f}};
#pragma unroll
  for (int i = 0; i < 2; ++i)
#pragma unroll
    for (int j = 0; j < 2; ++j) {
      const int nc = n0 + nw + 16 * j + ln;
#pragma unroll
      for (int r = 0; r < 4; ++r) {
        const int row = m0 + mw + 16 * i + quad * 4 + r;
        const size_t idx = (size_t)row * D_ + nc;
        float v = acc[i][j][r] + bj[j] + res[idx];
        out[idx] = v;
        if constexpr (DUAL) obf[idx] = f2bf(v);
        if constexpr (MEAN) psum[i][j] += v;
      }
    }
  if constexpr (MEAN) {
    __shared__ float ssum[16][64];
#pragma unroll
    for (int i = 0; i < 2; ++i)
#pragma unroll
      for (int j = 0; j < 2; ++j) {
        const int rg = (wv & 1) * 8 + i * 4 + quad;
        const int cl = (wv >> 1) * 32 + j * 16 + ln;
        ssum[rg][cl] = psum[i][j];
      }
    __syncthreads();
    if (tid < 64) {
      float s = 0.f;
#pragma unroll
      for (int rg = 0; rg < 16; ++rg) s += ssum[rg][tid];
      const int b = m0 >> 10;
      atomicAdd(&g_mean[b * D_ + n0 + tid], s);
    }
  }
}

__global__ __launch_bounds__(256) void k_mix1g(const float* __restrict__ bias) {
  gemm_bf16_dev<true, false>(g_gelubf, g_w1bf, bias, g_h, g_h2, g_hbf);
}
__global__ __launch_bounds__(256) void k_mix2g(const float* __restrict__ bias) {
  gemm_bf16_dev<false, true>(g_gelubf, g_w2bf, bias, g_h2, g_h, nullptr);
}

// ---------------------------------------------------------------------------
// Head: mean (column sums pre-accumulated in g_mean) + out-proj. Separate
// dispatch — the stream boundary is the cheap cross-block handoff (R11 lesson).
// ---------------------------------------------------------------------------
__global__ __launch_bounds__(512) void k_finalB(const float* out_w, const float* out_b,
                                                float* out) {
  __shared__ float sm[D_];
  __shared__ float sp[DOUT_ * 16];
  const int b = blockIdx.x, tid = threadIdx.x;
  sm[tid] = g_mean[b * D_ + tid] * (1.0f / L_);
  __syncthreads();
  if (tid < DOUT_ * 16) {
    int o = tid >> 4, seg = tid & 15;
    float p = 0.0f;
#pragma unroll
    for (int i = 0; i < 32; ++i)
      p += sm[seg * 32 + i] * out_w[o * D_ + seg * 32 + i];
    sp[tid] = p;
  }
  __syncthreads();
  if (tid < DOUT_) {
    float v = out_b[tid];
#pragma unroll
    for (int i = 0; i < 16; ++i) v += sp[tid * 16 + i];
    out[b * DOUT_ + tid] = v;
  }
}

// ---------------------------------------------------------------------------
// Shared piece: stage hbf chunk-tile to LDS, run fused xdbl MFMA into sx.
// B-fragments read directly from global xproj (64 KB, L2-resident).
// sx[l][0:32)=dt, [32:48)=B, [48:64)=C.
// ---------------------------------------------------------------------------
__device__ __forceinline__ void load_A(const float* __restrict__ Alog, int d,
                                       float* A) {
#pragma unroll
  for (int n = 0; n < 16; n += 4) {
    float4 t = *(const float4*)&Alog[d * N_ + n];
    A[n + 0] = -__expf(t.x); A[n + 1] = -__expf(t.y);
    A[n + 2] = -__expf(t.z); A[n + 3] = -__expf(t.w);
  }
}

__device__ __forceinline__ void xdbl_tile(const ushort_t* __restrict__ xpbf,
                                          int row0, int tid,
                                          ushort_t (*As)[520], float (*sx)[65]) {
  const int lane = tid & 63;
  const int wv   = tid >> 6;
  const int quad = lane >> 4;
  const int ln   = lane & 15;
#pragma unroll
  for (int i = 0; i < 2; ++i) {
    int idx = tid + i * 512;
    int m = idx >> 6, kq = (idx & 63) << 3;
    *(float4*)&As[m][kq] = *(const float4*)&g_hbf[(size_t)(row0 + m) * 512 + kq];
  }
  __syncthreads();
  if (wv < 4) {
    f4_t acc = {};
#pragma unroll
    for (int k0 = 0; k0 < 512; k0 += 32) {
      bf8_t a  = *(const bf8_t*)&As[ln][k0 + quad * 8];
      bf8_t bb = *(const bf8_t*)&xpbf[(size_t)(wv * 16 + ln) * 512 + k0 + quad * 8];
      acc = __builtin_amdgcn_mfma_f32_16x16x32_bf16(a, bb, acc, 0, 0, 0);
    }
#pragma unroll
    for (int r = 0; r < 4; ++r)
      sx[quad * 4 + r][wv * 16 + ln] = acc[r];
  }
  __syncthreads();
}

// ---------------------------------------------------------------------------
// p1f: fused xdbl + delta-proj + local scan from 0 -> stL/sumd.
// ---------------------------------------------------------------------------
__device__ __forceinline__ void p1f_dev(const float* __restrict__ h,
                                        const ushort_t* __restrict__ xpbf,
                                        const float* __restrict__ dtw,
                                        const float* __restrict__ dtb,
                                        const float* __restrict__ Alog) {
  __shared__ ushort_t As[16][520];
  __shared__ float    sx[16][65];
  const int tid  = threadIdx.x;      // 0..511
  const int c    = blockIdx.x & (CN_ - 1);
  const int b    = blockIdx.x >> 6;
  const int row0 = b * L_ + c * CL_;
  const int d    = tid;

  float w[32];
#pragma unroll
  for (int r = 0; r < 32; r += 4) {
    float4 t = *(const float4*)&dtw[d * R_ + r];
    w[r] = t.x; w[r + 1] = t.y; w[r + 2] = t.z; w[r + 3] = t.w;
  }
  const float bias = dtb[d];
  float A[16];
  load_A(Alog, d, A);

  xdbl_tile(xpbf, row0, tid, As, sx);

  float st[16] = {};
  float sumd = 0.0f;
#pragma unroll
  for (int l = 0; l < CL_; ++l) {
    float acc2 = bias;
#pragma unroll
    for (int k = 0; k < 32; ++k) acc2 = fmaf(sx[l][k], w[k], acc2);
    const float delta = softplus_f(acc2);
    const float dh = delta * h[(size_t)(row0 + l) * D_ + d];
    sumd += delta;
#pragma unroll
    for (int n = 0; n < 16; ++n) {
      float dA = __expf(delta * A[n]);
      st[n] = fmaf(dA, st[n], dh * sx[l][32 + n]);
    }
  }
  const size_t o = ((size_t)(b * CN_ + c) * D_ + d) * N_;
#pragma unroll
  for (int n = 0; n < 16; n += 4)
    *(float4*)&g_stL[o + n] = make_float4(st[n], st[n+1], st[n+2], st[n+3]);
  g_sumd[(b * CN_ + c) * D_ + d] = sumd;
}

__global__ __launch_bounds__(512, 4) void k_p1f_1(const float* dtw, const float* dtb,
                                                  const float* Alog) {
  p1f_dev(g_h, g_xp1bf, dtw, dtb, Alog);
}
__global__ __launch_bounds__(512, 4) void k_p1f_2(const float* dtw, const float* dtb,
                                                  const float* Alog) {
  p1f_dev(g_h2, g_xp2bf, dtw, dtb, Alog);
}

// ---------------------------------------------------------------------------
// carry: H_c = exp(A*sumd_c) * H_{c-1} + S_c; 1 thread per (b,d,n) chain,
// 16-wide prefetch. Full-grid parallelism.
// ---------------------------------------------------------------------------
__global__ __launch_bounds__(256) void k_scan_carry(const float* __restrict__ Alog) {
  const int g = blockIdx.x * 256 + threadIdx.x;     // B*D*N = 32768 threads
  const int n = g & 15;
  const int d = (g >> 4) & (D_ - 1);
  const int b = g >> 13;
  const float A = -__expf(Alog[d * N_ + n]);
  float carry = 0.0f;
#pragma unroll
  for (int c0 = 0; c0 < CN_; c0 += 16) {
    float s[16], p[16];
#pragma unroll
    for (int j = 0; j < 16; ++j) {
      s[j] = g_stL[((size_t)(b * CN_ + c0 + j) * D_ + d) * N_ + n];
      p[j] = g_sumd[(b * CN_ + c0 + j) * D_ + d];
    }
#pragma unroll
    for (int j = 0; j < 16; ++j) {
      g_carry[((size_t)(b * CN_ + c0 + j) * D_ + d) * N_ + n] = carry;
      carry = fmaf(__expf(A * p[j]), carry, s[j]);
    }
  }
}

// ---------------------------------------------------------------------------
// p2f: fused xdbl (recomputed, bit-identical) + carry-seeded re-scan + emit.
// ---------------------------------------------------------------------------
__device__ __forceinline__ void p2f_dev(const float* __restrict__ h,
                                        const ushort_t* __restrict__ xpbf,
                                        const float* __restrict__ dtw,
                                        const float* __restrict__ dtb,
                                        const float* __restrict__ Alog,
                                        const float* __restrict__ Dp,
                                        ushort_t* __restrict__ ybf) {
  __shared__ ushort_t As[16][520];
  __shared__ float    sx[16][65];
  const int tid  = threadIdx.x;
  const int c    = blockIdx.x & (CN_ - 1);
  const int b    = blockIdx.x >> 6;
  const int row0 = b * L_ + c * CL_;
  const int d    = tid;

  float w[32];
#pragma unroll
  for (int r = 0; r < 32; r += 4) {
    float4 t = *(const float4*)&dtw[d * R_ + r];
    w[r] = t.x; w[r + 1] = t.y; w[r + 2] = t.z; w[r + 3] = t.w;
  }
  const float bias = dtb[d];
  float A[16];
  load_A(Alog, d, A);
  const float Dpv = Dp[d];

  xdbl_tile(xpbf, row0, tid, As, sx);

  float st[16];
  const size_t o = ((size_t)(b * CN_ + c) * D_ + d) * N_;
#pragma unroll
  for (int n = 0; n < 16; n += 4) {
    float4 t = *(const float4*)&g_carry[o + n];
    st[n] = t.x; st[n+1] = t.y; st[n+2] = t.z; st[n+3] = t.w;
  }
#pragma unroll
  for (int l = 0; l < CL_; ++l) {
    float acc2 = bias;
#pragma unroll
    for (int k = 0; k < 32; ++k) acc2 = fmaf(sx[l][k], w[k], acc2);
    const float delta = softplus_f(acc2);     // bit-identical to p1f
    const float hv = h[(size_t)(row0 + l) * D_ + d];
    const float dh = delta * hv;
    float y = 0.0f;
#pragma unroll
    for (int n = 0; n < 16; ++n) {
      float dA = __expf(delta * A[n]);
      st[n] = fmaf(dA, st[n], dh * sx[l][32 + n]);
      y = fmaf(st[n], sx[l][48 + n], y);
    }
    ybf[(size_t)(row0 + l) * D_ + d] = f2bf(gelu_f(y + hv * Dpv));
  }
}

__global__ __launch_bounds__(512, 4) void k_p2f_1(const float* dtw, const float* dtb,
                                                  const float* Alog, const float* Dp) {
  p2f_dev(g_h, g_xp1bf, dtw, dtb, Alog, Dp, g_gelubf);
}
__global__ __launch_bounds__(512, 4) void k_p2f_2(const float* dtw, const float* dtb,
                                                  const float* Alog, const float* Dp) {
  p2f_dev(g_h2, g_xp2bf, dtw, dtb, Alog, Dp, g_gelubf);
}

extern "C" void kernel_launch(void* const* d_in, const int* in_sizes, int n_in,
                              void* d_out, int out_size, void* d_ws, size_t ws_size,
                              hipStream_t stream) {
  const float* x        = (const float*)d_in[0];
  const float* W_in     = (const float*)d_in[1];
  const float* b_in     = (const float*)d_in[2];
  const float* mix1_w   = (const float*)d_in[3];
  const float* mix1_b   = (const float*)d_in[4];
  const float* mix2_w   = (const float*)d_in[5];
  const float* mix2_b   = (const float*)d_in[6];
  const float* out_w    = (const float*)d_in[7];
  const float* out_b    = (const float*)d_in[8];
  const float* m1_xproj = (const float*)d_in[9];
  const float* m1_dtw   = (const float*)d_in[10];
  const float* m1_dtb   = (const float*)d_in[11];
  const float* m1_Alog  = (const float*)d_in[12];
  const float* m1_D     = (const float*)d_in[13];
  const float* m2_xproj = (const float*)d_in[14];
  const float* m2_dtw   = (const float*)d_in[15];
  const float* m2_dtb   = (const float*)d_in[16];
  const float* m2_Alog  = (const float*)d_in[17];
  const float* m2_D     = (const float*)d_in[18];
  float* out = (float*)d_out;

  const int gScan  = B_ * CN_;                // 256
  const int gCarry = (B_ * D_ * N_) / 256;    // 128
  const int gMix   = (M_ / 64) * (D_ / 64);   // 512

  k_pre<<<1089, 256, 0, stream>>>(x, W_in, b_in, mix1_w, mix2_w, m1_xproj, m2_xproj);

  // ---- layer 1 ----
  k_p1f_1     <<<gScan,  512, 0, stream>>>(m1_dtw, m1_dtb, m1_Alog);
  k_scan_carry<<<gCarry, 256, 0, stream>>>(m1_Alog);
  k_p2f_1     <<<gScan,  512, 0, stream>>>(m1_dtw, m1_dtb, m1_Alog, m1_D);
  k_mix1g     <<<gMix,   256, 0, stream>>>(mix1_b);
  // ---- layer 2 ----
  k_p1f_2     <<<gScan,  512, 0, stream>>>(m2_dtw, m2_dtb, m2_Alog);
  k_scan_carry<<<gCarry, 256, 0, stream>>>(m2_Alog);
  k_p2f_2     <<<gScan,  512, 0, stream>>>(m2_dtw, m2_dtb, m2_Alog, m2_D);
  k_mix2g     <<<gMix,   256, 0, stream>>>(mix2_b);
  // ---- head ----
  k_finalB<<<B_, 512, 0, stream>>>(out_w, out_b, out);
}